// Round 15
// baseline (231.432 us; speedup 1.0000x reference)
//
#include <hip/hip_runtime.h>
#include <hip/hip_bf16.h>

#define N_NODES 20000
#define N_EDGES 320000
#define M_PAD   20096   // 157 * 128
#define NB_SCAN 79      // ceil(20000/256)
#define ECAP    2048    // LDS edge-stage capacity per block (16 KB)

typedef __attribute__((ext_vector_type(8))) short short8;
typedef __attribute__((ext_vector_type(4))) float f32x4;

__device__ __forceinline__ float b2f(short s){
  union { unsigned u; float f; } c;
  c.u = ((unsigned)(unsigned short)s) << 16;
  return c.f;
}
__device__ __forceinline__ short f2b(float f){
  union { float f; unsigned u; } c;
  c.f = f;
  unsigned r = (c.u + 0x7fffu + ((c.u >> 16) & 1u)) >> 16;
  return (short)r;
}

// async global(16B/lane) -> LDS (wave-uniform base + lane*16)
__device__ __forceinline__ void gload16(const void* g, void* l){
  __builtin_amdgcn_global_load_lds((const __attribute__((address_space(1))) void*)g,
                                   (__attribute__((address_space(3))) void*)l,
                                   16, 0, 0);
}

// ---------------- utility ----------------
__global__ void k_zero_i(int* p, int n){
  int i = blockIdx.x * 256 + threadIdx.x;
  if (i < n) p[i] = 0;
}

// ---------------- merged independent work: deg | wt3 | xbv96 ----------------
__device__ __forceinline__ void wt_one(int idx, const float* W0, const float* W1,
                                       const float* W2, short* WT,
                                       int cin, int cout, int Kp){
  int Kpad = 3 * Kp;
  int n = idx / Kpad;
  int k = idx - n * Kpad;
  int g = k / Kp;
  int kk = k - g * Kp;
  short v = 0;
  if (kk < cin){
    const float* W = (g == 0) ? W0 : ((g == 1) ? W1 : W2);
    v = f2b(W[(long long)kk * cout + n]);
  }
  WT[idx] = v;
}

// blocks [0,1250): deg; [1250,3314): wt3 (528384 el); [3314,4256): xbv96 (241152 el)
__global__ __launch_bounds__(256)
void k_mega(const int* row, int* deg,
            const float* W00, const float* W01, const float* W02, short* WT0,
            const float* W10, const float* W11, const float* W12, short* WT1,
            const float* W20, const float* W21, const float* W22, short* WT2,
            const float* v, short* B0){
  int b = blockIdx.x;
  if (b < 1250){
    int e = b * 256 + threadIdx.x;
    if (e < N_EDGES) atomicAdd(&deg[row[e]], 1);
  } else if (b < 3314){
    int idx = (b - 1250) * 256 + threadIdx.x;
    if (idx < 36864){
      wt_one(idx, W00, W01, W02, WT0, 86, 128, 96);
    } else if (idx < 36864 + 98304){
      wt_one(idx - 36864, W10, W11, W12, WT1, 128, 256, 128);
    } else if (idx < 528384){
      wt_one(idx - 36864 - 98304, W20, W21, W22, WT2, 256, 512, 256);
    }
  } else {
    int gl = (b - 3314) * 256 + threadIdx.x;
    int node = gl / 12;
    if (node >= M_PAD) return;
    int c0 = (gl - node * 12) * 8;
    short8 o;
    #pragma unroll
    for (int t = 0; t < 8; t++){
      int c = c0 + t;
      float val = (node < N_NODES && c < 86) ? v[(long long)node * 86 + c] : 0.0f;
      o[t] = f2b(val);
    }
    *(short8*)&B0[(long long)node * 96 + c0] = o;
  }
}

// ---------------- CSR build (3-phase scan) ----------------
__global__ __launch_bounds__(256)
void k_scan1(const int* deg, int* offs, int* bsum){
  __shared__ int part[256];
  int t = threadIdx.x;
  int b = blockIdx.x;
  int i = b * 256 + t;
  int v = (i < N_NODES) ? deg[i] : 0;
  part[t] = v;
  __syncthreads();
  for (int off = 1; off < 256; off <<= 1){
    int u = (t >= off) ? part[t - off] : 0;
    __syncthreads();
    if (t >= off) part[t] += u;
    __syncthreads();
  }
  if (i < N_NODES) offs[i] = part[t] - v;
  if (t == 255) bsum[b] = part[255];
}

__global__ __launch_bounds__(128)
void k_scan2(int* bsum){
  __shared__ int part[128];
  int t = threadIdx.x;
  int v = (t < NB_SCAN) ? bsum[t] : 0;
  part[t] = v;
  __syncthreads();
  for (int off = 1; off < 128; off <<= 1){
    int u = (t >= off) ? part[t - off] : 0;
    __syncthreads();
    if (t >= off) part[t] += u;
    __syncthreads();
  }
  if (t < NB_SCAN) bsum[t] = part[t] - v;
}

__global__ __launch_bounds__(256)
void k_scan3(const int* deg, int* offs, const int* bsum, float* dinv){
  int t = threadIdx.x;
  int b = blockIdx.x;
  int i = b * 256 + t;
  if (i < N_NODES){
    offs[i] += bsum[b];
    int d = deg[i];
    dinv[i] = (d > 0) ? rsqrtf((float)d) : 0.0f;
  }
  if (b == 0 && t == 0) offs[N_NODES] = N_EDGES;
}

// packed edge: ec[pos] = (w, bitcast(col))
__global__ void k_fill(const int* row, const int* col, const int* offs,
                       int* cursor, const float* dinv, float2* ec){
  int e = blockIdx.x * 256 + threadIdx.x;
  if (e >= N_EDGES) return;
  int r = row[e];
  int c = col[e];
  int pos = offs[r] + atomicAdd(&cursor[r], 1);
  ec[pos] = make_float2(-dinv[r] * dinv[c], __int_as_float(c));
}

// ---------------- staging: f32 x -> bf16 padded Xb ----------------
__global__ __launch_bounds__(256)
void k_xbv(const float* x, short* Xb, int cin, int lgLpn, int lda){
  long long gl = (long long)blockIdx.x * 256 + threadIdx.x;
  int node = (int)(gl >> lgLpn);
  if (node >= M_PAD) return;
  int c0 = ((int)gl & ((1 << lgLpn) - 1)) * 8;
  short8 o;
  if (node < N_NODES && (cin & 3) == 0 && c0 + 8 <= cin){
    f32x4 xa = *(const f32x4*)&x[(long long)node * cin + c0];
    f32x4 xb = *(const f32x4*)&x[(long long)node * cin + c0 + 4];
    o[0] = f2b(xa[0]); o[1] = f2b(xa[1]); o[2] = f2b(xa[2]); o[3] = f2b(xa[3]);
    o[4] = f2b(xb[0]); o[5] = f2b(xb[1]); o[6] = f2b(xb[2]); o[7] = f2b(xb[3]);
  } else {
    #pragma unroll
    for (int t = 0; t < 8; t++){
      int c = c0 + t;
      float val = (node < N_NODES && c < cin) ? x[(long long)node * cin + c] : 0.0f;
      o[t] = f2b(val);
    }
  }
  *(short8*)&Xb[(long long)node * lda + c0] = o;
}

// ---------------- LDS-staged lhat kernels ----------------
__global__ __launch_bounds__(256)
void k_lhat1v(const short* X, const int* offs, const float2* ec,
              short* Z1, int lgLpn, int lda){
  __shared__ float2 lec[ECAP];
  long long gl0 = (long long)blockIdx.x * 256;
  long long gl = gl0 + threadIdx.x;
  int node = (int)(gl >> lgLpn);
  int node0 = (int)(gl0 >> lgLpn);
  int nodeL = (int)((gl0 + 255) >> lgLpn);
  if (nodeL > N_NODES - 1) nodeL = N_NODES - 1;
  int s0 = 0;
  int cnt = 0;
  if (node0 < N_NODES){
    s0 = offs[node0];
    cnt = offs[nodeL + 1] - s0;
  }
  int useLds = (cnt <= ECAP);
  if (useLds){
    for (int i = threadIdx.x; i < cnt; i += 256)
      lec[i] = ec[s0 + i];
  }
  __syncthreads();
  if (node >= N_NODES) return;
  int c0 = ((int)gl & ((1 << lgLpn) - 1)) * 8;
  int s = offs[node];
  int e = offs[node + 1];
  float a[8];
  #pragma unroll
  for (int t = 0; t < 8; t++) a[t] = 0.0f;
  if (useLds){
    int j = s - s0;
    int ee = e - s0;
    for (; j + 4 <= ee; j += 4){
      float2 e0 = lec[j];     float2 e1 = lec[j + 1];
      float2 e2 = lec[j + 2]; float2 e3 = lec[j + 3];
      short8 v0 = *(const short8*)&X[(long long)__float_as_int(e0.y) * lda + c0];
      short8 v1 = *(const short8*)&X[(long long)__float_as_int(e1.y) * lda + c0];
      short8 v2 = *(const short8*)&X[(long long)__float_as_int(e2.y) * lda + c0];
      short8 v3 = *(const short8*)&X[(long long)__float_as_int(e3.y) * lda + c0];
      #pragma unroll
      for (int t = 0; t < 8; t++)
        a[t] += e0.x * b2f(v0[t]) + e1.x * b2f(v1[t]) + e2.x * b2f(v2[t]) + e3.x * b2f(v3[t]);
    }
    for (; j < ee; j++){
      float2 e0 = lec[j];
      short8 v0 = *(const short8*)&X[(long long)__float_as_int(e0.y) * lda + c0];
      #pragma unroll
      for (int t = 0; t < 8; t++) a[t] += e0.x * b2f(v0[t]);
    }
  } else {
    for (int j = s; j < e; j++){
      float2 e0 = ec[j];
      short8 v0 = *(const short8*)&X[(long long)__float_as_int(e0.y) * lda + c0];
      #pragma unroll
      for (int t = 0; t < 8; t++) a[t] += e0.x * b2f(v0[t]);
    }
  }
  short8 o;
  #pragma unroll
  for (int t = 0; t < 8; t++) o[t] = f2b(a[t]);
  *(short8*)&Z1[(long long)node * lda + c0] = o;
}

__global__ __launch_bounds__(256)
void k_lhat2v(const float* x, const short* Z1, const int* offs, const float2* ec,
              short* Z2, int cin, int lgLpn, int lda){
  __shared__ float2 lec[ECAP];
  long long gl0 = (long long)blockIdx.x * 256;
  long long gl = gl0 + threadIdx.x;
  int node = (int)(gl >> lgLpn);
  int node0 = (int)(gl0 >> lgLpn);
  int nodeL = (int)((gl0 + 255) >> lgLpn);
  if (nodeL > N_NODES - 1) nodeL = N_NODES - 1;
  int s0 = 0;
  int cnt = 0;
  if (node0 < N_NODES){
    s0 = offs[node0];
    cnt = offs[nodeL + 1] - s0;
  }
  int useLds = (cnt <= ECAP);
  if (useLds){
    for (int i = threadIdx.x; i < cnt; i += 256)
      lec[i] = ec[s0 + i];
  }
  __syncthreads();
  if (node >= N_NODES) return;
  int c0 = ((int)gl & ((1 << lgLpn) - 1)) * 8;
  int s = offs[node];
  int e = offs[node + 1];
  float a[8];
  #pragma unroll
  for (int t = 0; t < 8; t++) a[t] = 0.0f;
  if (useLds){
    int j = s - s0;
    int ee = e - s0;
    for (; j + 4 <= ee; j += 4){
      float2 e0 = lec[j];     float2 e1 = lec[j + 1];
      float2 e2 = lec[j + 2]; float2 e3 = lec[j + 3];
      short8 v0 = *(const short8*)&Z1[(long long)__float_as_int(e0.y) * lda + c0];
      short8 v1 = *(const short8*)&Z1[(long long)__float_as_int(e1.y) * lda + c0];
      short8 v2 = *(const short8*)&Z1[(long long)__float_as_int(e2.y) * lda + c0];
      short8 v3 = *(const short8*)&Z1[(long long)__float_as_int(e3.y) * lda + c0];
      #pragma unroll
      for (int t = 0; t < 8; t++)
        a[t] += e0.x * b2f(v0[t]) + e1.x * b2f(v1[t]) + e2.x * b2f(v2[t]) + e3.x * b2f(v3[t]);
    }
    for (; j < ee; j++){
      float2 e0 = lec[j];
      short8 v0 = *(const short8*)&Z1[(long long)__float_as_int(e0.y) * lda + c0];
      #pragma unroll
      for (int t = 0; t < 8; t++) a[t] += e0.x * b2f(v0[t]);
    }
  } else {
    for (int j = s; j < e; j++){
      float2 e0 = ec[j];
      short8 v0 = *(const short8*)&Z1[(long long)__float_as_int(e0.y) * lda + c0];
      #pragma unroll
      for (int t = 0; t < 8; t++) a[t] += e0.x * b2f(v0[t]);
    }
  }
  float xv[8];
  if ((cin & 3) == 0 && c0 + 8 <= cin){
    f32x4 xa = *(const f32x4*)&x[(long long)node * cin + c0];
    f32x4 xb = *(const f32x4*)&x[(long long)node * cin + c0 + 4];
    xv[0] = xa[0]; xv[1] = xa[1]; xv[2] = xa[2]; xv[3] = xa[3];
    xv[4] = xb[0]; xv[5] = xb[1]; xv[6] = xb[2]; xv[7] = xb[3];
  } else {
    #pragma unroll
    for (int t = 0; t < 8; t++){
      int c = c0 + t;
      xv[t] = (c < cin) ? x[(long long)node * cin + c] : 0.0f;
    }
  }
  short8 o;
  #pragma unroll
  for (int t = 0; t < 8; t++) o[t] = f2b(2.0f * a[t] - xv[t]);
  *(short8*)&Z2[(long long)node * lda + c0] = o;
}

// ---------------- layer-0 narrow lhat variants: lda=96, 12 lanes/node ---------
__global__ __launch_bounds__(256)
void k_lhat1v96(const short* X, const int* offs, const float2* ec, short* Z1){
  __shared__ float2 lec[ECAP];
  int gl0 = blockIdx.x * 256;
  int gl = gl0 + threadIdx.x;
  int node = gl / 12;
  int node0 = gl0 / 12;
  int nodeL = (gl0 + 255) / 12;
  if (nodeL > N_NODES - 1) nodeL = N_NODES - 1;
  int s0 = 0;
  int cnt = 0;
  if (node0 < N_NODES){
    s0 = offs[node0];
    cnt = offs[nodeL + 1] - s0;
  }
  int useLds = (cnt <= ECAP);
  if (useLds){
    for (int i = threadIdx.x; i < cnt; i += 256)
      lec[i] = ec[s0 + i];
  }
  __syncthreads();
  if (node >= N_NODES) return;
  int c0 = (gl - node * 12) * 8;
  int s = offs[node];
  int e = offs[node + 1];
  float a[8];
  #pragma unroll
  for (int t = 0; t < 8; t++) a[t] = 0.0f;
  if (useLds){
    int j = s - s0;
    int ee = e - s0;
    for (; j + 4 <= ee; j += 4){
      float2 e0 = lec[j];     float2 e1 = lec[j + 1];
      float2 e2 = lec[j + 2]; float2 e3 = lec[j + 3];
      short8 v0 = *(const short8*)&X[(long long)__float_as_int(e0.y) * 96 + c0];
      short8 v1 = *(const short8*)&X[(long long)__float_as_int(e1.y) * 96 + c0];
      short8 v2 = *(const short8*)&X[(long long)__float_as_int(e2.y) * 96 + c0];
      short8 v3 = *(const short8*)&X[(long long)__float_as_int(e3.y) * 96 + c0];
      #pragma unroll
      for (int t = 0; t < 8; t++)
        a[t] += e0.x * b2f(v0[t]) + e1.x * b2f(v1[t]) + e2.x * b2f(v2[t]) + e3.x * b2f(v3[t]);
    }
    for (; j < ee; j++){
      float2 e0 = lec[j];
      short8 v0 = *(const short8*)&X[(long long)__float_as_int(e0.y) * 96 + c0];
      #pragma unroll
      for (int t = 0; t < 8; t++) a[t] += e0.x * b2f(v0[t]);
    }
  } else {
    for (int j = s; j < e; j++){
      float2 e0 = ec[j];
      short8 v0 = *(const short8*)&X[(long long)__float_as_int(e0.y) * 96 + c0];
      #pragma unroll
      for (int t = 0; t < 8; t++) a[t] += e0.x * b2f(v0[t]);
    }
  }
  short8 o;
  #pragma unroll
  for (int t = 0; t < 8; t++) o[t] = f2b(a[t]);
  *(short8*)&Z1[(long long)node * 96 + c0] = o;
}

__global__ __launch_bounds__(256)
void k_lhat2v96(const float* x, const short* Z1, const int* offs,
                const float2* ec, short* Z2){
  __shared__ float2 lec[ECAP];
  int gl0 = blockIdx.x * 256;
  int gl = gl0 + threadIdx.x;
  int node = gl / 12;
  int node0 = gl0 / 12;
  int nodeL = (gl0 + 255) / 12;
  if (nodeL > N_NODES - 1) nodeL = N_NODES - 1;
  int s0 = 0;
  int cnt = 0;
  if (node0 < N_NODES){
    s0 = offs[node0];
    cnt = offs[nodeL + 1] - s0;
  }
  int useLds = (cnt <= ECAP);
  if (useLds){
    for (int i = threadIdx.x; i < cnt; i += 256)
      lec[i] = ec[s0 + i];
  }
  __syncthreads();
  if (node >= N_NODES) return;
  int c0 = (gl - node * 12) * 8;
  int s = offs[node];
  int e = offs[node + 1];
  float a[8];
  #pragma unroll
  for (int t = 0; t < 8; t++) a[t] = 0.0f;
  if (useLds){
    int j = s - s0;
    int ee = e - s0;
    for (; j + 4 <= ee; j += 4){
      float2 e0 = lec[j];     float2 e1 = lec[j + 1];
      float2 e2 = lec[j + 2]; float2 e3 = lec[j + 3];
      short8 v0 = *(const short8*)&Z1[(long long)__float_as_int(e0.y) * 96 + c0];
      short8 v1 = *(const short8*)&Z1[(long long)__float_as_int(e1.y) * 96 + c0];
      short8 v2 = *(const short8*)&Z1[(long long)__float_as_int(e2.y) * 96 + c0];
      short8 v3 = *(const short8*)&Z1[(long long)__float_as_int(e3.y) * 96 + c0];
      #pragma unroll
      for (int t = 0; t < 8; t++)
        a[t] += e0.x * b2f(v0[t]) + e1.x * b2f(v1[t]) + e2.x * b2f(v2[t]) + e3.x * b2f(v3[t]);
    }
    for (; j < ee; j++){
      float2 e0 = lec[j];
      short8 v0 = *(const short8*)&Z1[(long long)__float_as_int(e0.y) * 96 + c0];
      #pragma unroll
      for (int t = 0; t < 8; t++) a[t] += e0.x * b2f(v0[t]);
    }
  } else {
    for (int j = s; j < e; j++){
      float2 e0 = ec[j];
      short8 v0 = *(const short8*)&Z1[(long long)__float_as_int(e0.y) * 96 + c0];
      #pragma unroll
      for (int t = 0; t < 8; t++) a[t] += e0.x * b2f(v0[t]);
    }
  }
  float xv[8];
  #pragma unroll
  for (int t = 0; t < 8; t++){
    int c = c0 + t;
    xv[t] = (c < 86) ? x[(long long)node * 86 + c] : 0.0f;
  }
  short8 o;
  #pragma unroll
  for (int t = 0; t < 8; t++) o[t] = f2b(2.0f * a[t] - xv[t]);
  *(short8*)&Z2[(long long)node * 96 + c0] = o;
}

// ---------------- MFMA GEMM: 2-phase prefetch (double-buffered LDS) -----------
// Per K-step: barrier -> issue next-step global_load_lds into buf^1 (overlaps
// with compute) -> ds_read buf + MFMA. One barrier per step; the barrier's
// vmcnt drain completes the PREVIOUS iteration's prefetch after a full
// compute phase of overlap.
__global__ __launch_bounds__(256)
void k_gemm(const short* A0, const short* A1, const short* A2,
            const short* BT,   // cout x 3Kext bf16 (row-major, K-contig)
            const float* bias, float* C, int lda, int Kext, int cout){
  __shared__ short aLds[2 * 128 * 32];
  __shared__ short bLds[2 * 128 * 32];
  int tid = threadIdx.x;
  int lane = tid & 63;
  int wave = tid >> 6;          // 0..3
  int wm = wave >> 1;
  int wn = wave & 1;
  int bm0 = blockIdx.x * 128;
  int bn0 = blockIdx.y * 128;
  int Kpad3 = 3 * Kext;

  int l4 = lane >> 2;                       // row within chunk 0..15
  int slotSrc = (lane & 3) ^ (l4 & 3);      // pre-swizzled source col slot

  f32x4 acc[4][4];
  for (int m = 0; m < 4; m++)
    for (int n = 0; n < 4; n++)
      acc[m][n] = (f32x4){0.0f, 0.0f, 0.0f, 0.0f};

  // prologue: stage (g=0, kt=0) into buf 0
  {
    const short* Ag = A0;
    const short* Bg = BT;
    #pragma unroll
    for (int cc = 0; cc < 2; cc++){
      int c = wave * 2 + cc;
      int row = c * 16 + l4;
      gload16(&Ag[(long long)(bm0 + row) * lda + slotSrc * 8], &aLds[c * 512]);
      gload16(&Bg[(long long)(bn0 + row) * Kpad3 + slotSrc * 8], &bLds[c * 512]);
    }
  }

  int cur = 0;
  for (int g = 0; g < 3; g++){
    for (int kt = 0; kt < Kext; kt += 32){
      __syncthreads();   // drains prefetch into buf cur; fences reads of buf cur^1

      // issue next-step prefetch into buf cur^1 (overlaps ds_read+MFMA below)
      int last = (g == 2) && (kt + 32 >= Kext);
      if (!last){
        int g2 = (kt + 32 < Kext) ? g : g + 1;
        int kt2 = (kt + 32 < Kext) ? kt + 32 : 0;
        const short* Ag2 = (g2 == 0) ? A0 : ((g2 == 1) ? A1 : A2);
        const short* Bg2 = BT + g2 * Kext;
        int nb = (cur ^ 1) * 4096;
        #pragma unroll
        for (int cc = 0; cc < 2; cc++){
          int c = wave * 2 + cc;
          int row = c * 16 + l4;
          gload16(&Ag2[(long long)(bm0 + row) * lda + kt2 + slotSrc * 8], &aLds[nb + c * 512]);
          gload16(&Bg2[(long long)(bn0 + row) * Kpad3 + kt2 + slotSrc * 8], &bLds[nb + c * 512]);
        }
      }

      int cb = cur * 4096;
      short8 af[4];
      short8 bfr[4];
      #pragma unroll
      for (int m = 0; m < 4; m++){
        int row = wm * 64 + m * 16 + (lane & 15);
        int slot = (lane >> 4) ^ (row & 3);
        af[m] = *(const short8*)&aLds[cb + row * 32 + slot * 8];
      }
      #pragma unroll
      for (int n = 0; n < 4; n++){
        int row = wn * 64 + n * 16 + (lane & 15);
        int slot = (lane >> 4) ^ (row & 3);
        bfr[n] = *(const short8*)&bLds[cb + row * 32 + slot * 8];
      }
      #pragma unroll
      for (int m = 0; m < 4; m++)
        #pragma unroll
        for (int n = 0; n < 4; n++)
          acc[m][n] = __builtin_amdgcn_mfma_f32_16x16x32_bf16(af[m], bfr[n], acc[m][n], 0, 0, 0);

      cur ^= 1;
    }
  }

  for (int m = 0; m < 4; m++){
    for (int n = 0; n < 4; n++){
      int gc = bn0 + wn * 64 + n * 16 + (lane & 15);
      float bv = bias[gc];
      for (int r = 0; r < 4; r++){
        int gr = bm0 + wm * 64 + m * 16 + (lane >> 4) * 4 + r;
        if (gr < N_NODES){
          float v2 = acc[m][n][r] + bv;
          if (v2 < 0.0f) v2 = 0.0f;
          C[(long long)gr * cout + gc] = v2;
        }
      }
    }
  }
}

extern "C" void kernel_launch(void* const* d_in, const int* in_sizes, int n_in,
                              void* d_out, int out_size, void* d_ws, size_t ws_size,
                              hipStream_t stream){
  const float* v = (const float*)d_in[0];
  const int* edges = (const int*)d_in[1];
  const int* row = edges;
  const int* col = edges + N_EDGES;

  const float* W00 = (const float*)d_in[2];
  const float* W01 = (const float*)d_in[3];
  const float* W02 = (const float*)d_in[4];
  const float* b0  = (const float*)d_in[5];
  const float* W10 = (const float*)d_in[6];
  const float* W11 = (const float*)d_in[7];
  const float* W12 = (const float*)d_in[8];
  const float* b1  = (const float*)d_in[9];
  const float* W20 = (const float*)d_in[10];
  const float* W21 = (const float*)d_in[11];
  const float* W22 = (const float*)d_in[12];
  const float* b2  = (const float*)d_in[13];

  // workspace layout (byte offsets, 256-aligned; ~36 MB)
  char* ws = (char*)d_ws;
  int* deg    = (int*)(ws + 0);                   // 20000 ints
  int* cursor = (int*)(ws + 80128);               // 20000
  int* offs   = (int*)(ws + 160256);              // 20001
  int* bsum   = (int*)(ws + 240640);              // 128
  float* dinv = (float*)(ws + 241152);            // 20000
  float2* ec  = (float2*)(ws + 321280);           // 320000 float2 = 2.56 MB
  short* B0  = (short*)(ws + 2881536);                         // M_PAD*256 bf16
  short* B1  = (short*)(ws + 2881536 + 10289152);
  short* B2  = (short*)(ws + 2881536 + 2 * 10289152);
  short* WT0 = (short*)(ws + 2881536 + 3 * 10289152);          // 128*288 bf16
  short* WT1 = (short*)(ws + 2881536 + 3 * 10289152 + 73728);  // 256*384 bf16
  short* WT2 = (short*)(ws + 2881536 + 3 * 10289152 + 73728 + 196608); // 512*768

  float* out = (float*)d_out;
  float* x1 = out;
  float* x2 = out + (long long)N_NODES * 128;
  float* x3 = out + (long long)N_NODES * (128 + 256);

  // CSR + weights + L0 staging (merged)
  k_zero_i<<<(40064 + 255) / 256, 256, 0, stream>>>(deg, 40064);  // deg+cursor
  k_mega<<<4256, 256, 0, stream>>>(row, deg,
                                   W00, W01, W02, WT0,
                                   W10, W11, W12, WT1,
                                   W20, W21, W22, WT2,
                                   v, B0);
  k_scan1<<<NB_SCAN, 256, 0, stream>>>(deg, offs, bsum);
  k_scan2<<<1, 128, 0, stream>>>(bsum);
  k_scan3<<<NB_SCAN, 256, 0, stream>>>(deg, offs, bsum, dinv);
  k_fill<<<(N_EDGES + 255) / 256, 256, 0, stream>>>(row, col, offs, cursor, dinv, ec);

  // grids
  int gNd96  = (int)(((long long)N_NODES * 12 + 255) / 256);
  int gXb128 = (int)(((long long)M_PAD * 16 + 255) / 256);
  int gXb256 = (int)(((long long)M_PAD * 32 + 255) / 256);
  int gNd128 = (int)(((long long)N_NODES * 16 + 255) / 256);
  int gNd256 = (int)(((long long)N_NODES * 32 + 255) / 256);

  // ---- layer 0: cin=86, Kext=96, lda=96, cout=128 (B0 staged by k_mega) ----
  k_lhat1v96<<<gNd96, 256, 0, stream>>>(B0, offs, ec, B1);
  k_lhat2v96<<<gNd96, 256, 0, stream>>>(v, B1, offs, ec, B2);
  {
    dim3 g(M_PAD / 128, 1);
    k_gemm<<<g, 256, 0, stream>>>(B0, B1, B2, WT0, b0, x1, 96, 96, 128);
  }

  // ---- layer 1: cin=128, Kext=128, lda=128, cout=256 ----
  k_xbv<<<gXb128, 256, 0, stream>>>(x1, B0, 128, 4, 128);
  k_lhat1v<<<gNd128, 256, 0, stream>>>(B0, offs, ec, B1, 4, 128);
  k_lhat2v<<<gNd128, 256, 0, stream>>>(x1, B1, offs, ec, B2, 128, 4, 128);
  {
    dim3 g(M_PAD / 128, 2);
    k_gemm<<<g, 256, 0, stream>>>(B0, B1, B2, WT1, b1, x2, 128, 128, 256);
  }

  // ---- layer 2: cin=256, Kext=256, lda=256, cout=512 ----
  k_xbv<<<gXb256, 256, 0, stream>>>(x2, B0, 256, 5, 256);
  k_lhat1v<<<gNd256, 256, 0, stream>>>(B0, offs, ec, B1, 5, 256);
  k_lhat2v<<<gNd256, 256, 0, stream>>>(x2, B1, offs, ec, B2, 256, 5, 256);
  {
    dim3 g(M_PAD / 128, 4);
    k_gemm<<<g, 256, 0, stream>>>(B0, B1, B2, WT2, b2, x3, 256, 256, 512);
  }
}

// Round 16
// 228.824 us; speedup vs baseline: 1.0114x; 1.0114x over previous
//
#include <hip/hip_runtime.h>
#include <hip/hip_bf16.h>

#define N_NODES 20000
#define N_EDGES 320000
#define M_PAD   20096   // 157 * 128
#define NB_SCAN 79      // ceil(20000/256)
#define ECAP    2048    // LDS edge-stage capacity per block (16 KB)

typedef __attribute__((ext_vector_type(8))) short short8;
typedef __attribute__((ext_vector_type(4))) float f32x4;

__device__ __forceinline__ float b2f(short s){
  union { unsigned u; float f; } c;
  c.u = ((unsigned)(unsigned short)s) << 16;
  return c.f;
}
__device__ __forceinline__ short f2b(float f){
  union { float f; unsigned u; } c;
  c.f = f;
  unsigned r = (c.u + 0x7fffu + ((c.u >> 16) & 1u)) >> 16;
  return (short)r;
}

// async global(16B/lane) -> LDS (wave-uniform base + lane*16)
__device__ __forceinline__ void gload16(const void* g, void* l){
  __builtin_amdgcn_global_load_lds((const __attribute__((address_space(1))) void*)g,
                                   (__attribute__((address_space(3))) void*)l,
                                   16, 0, 0);
}

// ---------------- utility ----------------
__global__ void k_zero_i(int* p, int n){
  int i = blockIdx.x * 256 + threadIdx.x;
  if (i < n) p[i] = 0;
}

// ---------------- merged independent work: deg | wt3 | xbv96 ----------------
__device__ __forceinline__ void wt_one(int idx, const float* W0, const float* W1,
                                       const float* W2, short* WT,
                                       int cin, int cout, int Kp){
  int Kpad = 3 * Kp;
  int n = idx / Kpad;
  int k = idx - n * Kpad;
  int g = k / Kp;
  int kk = k - g * Kp;
  short v = 0;
  if (kk < cin){
    const float* W = (g == 0) ? W0 : ((g == 1) ? W1 : W2);
    v = f2b(W[(long long)kk * cout + n]);
  }
  WT[idx] = v;
}

// blocks [0,1250): deg; [1250,3314): wt3 (528384 el); [3314,4256): xbv96 (241152 el)
__global__ __launch_bounds__(256)
void k_mega(const int* row, int* deg,
            const float* W00, const float* W01, const float* W02, short* WT0,
            const float* W10, const float* W11, const float* W12, short* WT1,
            const float* W20, const float* W21, const float* W22, short* WT2,
            const float* v, short* B0){
  int b = blockIdx.x;
  if (b < 1250){
    int e = b * 256 + threadIdx.x;
    if (e < N_EDGES) atomicAdd(&deg[row[e]], 1);
  } else if (b < 3314){
    int idx = (b - 1250) * 256 + threadIdx.x;
    if (idx < 36864){
      wt_one(idx, W00, W01, W02, WT0, 86, 128, 96);
    } else if (idx < 36864 + 98304){
      wt_one(idx - 36864, W10, W11, W12, WT1, 128, 256, 128);
    } else if (idx < 528384){
      wt_one(idx - 36864 - 98304, W20, W21, W22, WT2, 256, 512, 256);
    }
  } else {
    int gl = (b - 3314) * 256 + threadIdx.x;
    int node = gl / 12;
    if (node >= M_PAD) return;
    int c0 = (gl - node * 12) * 8;
    short8 o;
    #pragma unroll
    for (int t = 0; t < 8; t++){
      int c = c0 + t;
      float val = (node < N_NODES && c < 86) ? v[(long long)node * 86 + c] : 0.0f;
      o[t] = f2b(val);
    }
    *(short8*)&B0[(long long)node * 96 + c0] = o;
  }
}

// ---------------- CSR build (3-phase scan) ----------------
__global__ __launch_bounds__(256)
void k_scan1(const int* deg, int* offs, int* bsum){
  __shared__ int part[256];
  int t = threadIdx.x;
  int b = blockIdx.x;
  int i = b * 256 + t;
  int v = (i < N_NODES) ? deg[i] : 0;
  part[t] = v;
  __syncthreads();
  for (int off = 1; off < 256; off <<= 1){
    int u = (t >= off) ? part[t - off] : 0;
    __syncthreads();
    if (t >= off) part[t] += u;
    __syncthreads();
  }
  if (i < N_NODES) offs[i] = part[t] - v;
  if (t == 255) bsum[b] = part[255];
}

__global__ __launch_bounds__(128)
void k_scan2(int* bsum){
  __shared__ int part[128];
  int t = threadIdx.x;
  int v = (t < NB_SCAN) ? bsum[t] : 0;
  part[t] = v;
  __syncthreads();
  for (int off = 1; off < 128; off <<= 1){
    int u = (t >= off) ? part[t - off] : 0;
    __syncthreads();
    if (t >= off) part[t] += u;
    __syncthreads();
  }
  if (t < NB_SCAN) bsum[t] = part[t] - v;
}

__global__ __launch_bounds__(256)
void k_scan3(const int* deg, int* offs, const int* bsum, float* dinv){
  int t = threadIdx.x;
  int b = blockIdx.x;
  int i = b * 256 + t;
  if (i < N_NODES){
    offs[i] += bsum[b];
    int d = deg[i];
    dinv[i] = (d > 0) ? rsqrtf((float)d) : 0.0f;
  }
  if (b == 0 && t == 0) offs[N_NODES] = N_EDGES;
}

// packed edge: ec[pos] = (w, bitcast(col))
__global__ void k_fill(const int* row, const int* col, const int* offs,
                       int* cursor, const float* dinv, float2* ec){
  int e = blockIdx.x * 256 + threadIdx.x;
  if (e >= N_EDGES) return;
  int r = row[e];
  int c = col[e];
  int pos = offs[r] + atomicAdd(&cursor[r], 1);
  ec[pos] = make_float2(-dinv[r] * dinv[c], __int_as_float(c));
}

// ---------------- staging: f32 x -> bf16 padded Xb ----------------
__global__ __launch_bounds__(256)
void k_xbv(const float* x, short* Xb, int cin, int lgLpn, int lda){
  long long gl = (long long)blockIdx.x * 256 + threadIdx.x;
  int node = (int)(gl >> lgLpn);
  if (node >= M_PAD) return;
  int c0 = ((int)gl & ((1 << lgLpn) - 1)) * 8;
  short8 o;
  if (node < N_NODES && (cin & 3) == 0 && c0 + 8 <= cin){
    f32x4 xa = *(const f32x4*)&x[(long long)node * cin + c0];
    f32x4 xb = *(const f32x4*)&x[(long long)node * cin + c0 + 4];
    o[0] = f2b(xa[0]); o[1] = f2b(xa[1]); o[2] = f2b(xa[2]); o[3] = f2b(xa[3]);
    o[4] = f2b(xb[0]); o[5] = f2b(xb[1]); o[6] = f2b(xb[2]); o[7] = f2b(xb[3]);
  } else {
    #pragma unroll
    for (int t = 0; t < 8; t++){
      int c = c0 + t;
      float val = (node < N_NODES && c < cin) ? x[(long long)node * cin + c] : 0.0f;
      o[t] = f2b(val);
    }
  }
  *(short8*)&Xb[(long long)node * lda + c0] = o;
}

// ---------------- LDS-staged lhat kernels ----------------
__global__ __launch_bounds__(256)
void k_lhat1v(const short* X, const int* offs, const float2* ec,
              short* Z1, int lgLpn, int lda){
  __shared__ float2 lec[ECAP];
  long long gl0 = (long long)blockIdx.x * 256;
  long long gl = gl0 + threadIdx.x;
  int node = (int)(gl >> lgLpn);
  int node0 = (int)(gl0 >> lgLpn);
  int nodeL = (int)((gl0 + 255) >> lgLpn);
  if (nodeL > N_NODES - 1) nodeL = N_NODES - 1;
  int s0 = 0;
  int cnt = 0;
  if (node0 < N_NODES){
    s0 = offs[node0];
    cnt = offs[nodeL + 1] - s0;
  }
  int useLds = (cnt <= ECAP);
  if (useLds){
    for (int i = threadIdx.x; i < cnt; i += 256)
      lec[i] = ec[s0 + i];
  }
  __syncthreads();
  if (node >= N_NODES) return;
  int c0 = ((int)gl & ((1 << lgLpn) - 1)) * 8;
  int s = offs[node];
  int e = offs[node + 1];
  float a[8];
  #pragma unroll
  for (int t = 0; t < 8; t++) a[t] = 0.0f;
  if (useLds){
    int j = s - s0;
    int ee = e - s0;
    for (; j + 4 <= ee; j += 4){
      float2 e0 = lec[j];     float2 e1 = lec[j + 1];
      float2 e2 = lec[j + 2]; float2 e3 = lec[j + 3];
      short8 v0 = *(const short8*)&X[(long long)__float_as_int(e0.y) * lda + c0];
      short8 v1 = *(const short8*)&X[(long long)__float_as_int(e1.y) * lda + c0];
      short8 v2 = *(const short8*)&X[(long long)__float_as_int(e2.y) * lda + c0];
      short8 v3 = *(const short8*)&X[(long long)__float_as_int(e3.y) * lda + c0];
      #pragma unroll
      for (int t = 0; t < 8; t++)
        a[t] += e0.x * b2f(v0[t]) + e1.x * b2f(v1[t]) + e2.x * b2f(v2[t]) + e3.x * b2f(v3[t]);
    }
    for (; j < ee; j++){
      float2 e0 = lec[j];
      short8 v0 = *(const short8*)&X[(long long)__float_as_int(e0.y) * lda + c0];
      #pragma unroll
      for (int t = 0; t < 8; t++) a[t] += e0.x * b2f(v0[t]);
    }
  } else {
    for (int j = s; j < e; j++){
      float2 e0 = ec[j];
      short8 v0 = *(const short8*)&X[(long long)__float_as_int(e0.y) * lda + c0];
      #pragma unroll
      for (int t = 0; t < 8; t++) a[t] += e0.x * b2f(v0[t]);
    }
  }
  short8 o;
  #pragma unroll
  for (int t = 0; t < 8; t++) o[t] = f2b(a[t]);
  *(short8*)&Z1[(long long)node * lda + c0] = o;
}

__global__ __launch_bounds__(256)
void k_lhat2v(const float* x, const short* Z1, const int* offs, const float2* ec,
              short* Z2, int cin, int lgLpn, int lda){
  __shared__ float2 lec[ECAP];
  long long gl0 = (long long)blockIdx.x * 256;
  long long gl = gl0 + threadIdx.x;
  int node = (int)(gl >> lgLpn);
  int node0 = (int)(gl0 >> lgLpn);
  int nodeL = (int)((gl0 + 255) >> lgLpn);
  if (nodeL > N_NODES - 1) nodeL = N_NODES - 1;
  int s0 = 0;
  int cnt = 0;
  if (node0 < N_NODES){
    s0 = offs[node0];
    cnt = offs[nodeL + 1] - s0;
  }
  int useLds = (cnt <= ECAP);
  if (useLds){
    for (int i = threadIdx.x; i < cnt; i += 256)
      lec[i] = ec[s0 + i];
  }
  __syncthreads();
  if (node >= N_NODES) return;
  int c0 = ((int)gl & ((1 << lgLpn) - 1)) * 8;
  int s = offs[node];
  int e = offs[node + 1];
  float a[8];
  #pragma unroll
  for (int t = 0; t < 8; t++) a[t] = 0.0f;
  if (useLds){
    int j = s - s0;
    int ee = e - s0;
    for (; j + 4 <= ee; j += 4){
      float2 e0 = lec[j];     float2 e1 = lec[j + 1];
      float2 e2 = lec[j + 2]; float2 e3 = lec[j + 3];
      short8 v0 = *(const short8*)&Z1[(long long)__float_as_int(e0.y) * lda + c0];
      short8 v1 = *(const short8*)&Z1[(long long)__float_as_int(e1.y) * lda + c0];
      short8 v2 = *(const short8*)&Z1[(long long)__float_as_int(e2.y) * lda + c0];
      short8 v3 = *(const short8*)&Z1[(long long)__float_as_int(e3.y) * lda + c0];
      #pragma unroll
      for (int t = 0; t < 8; t++)
        a[t] += e0.x * b2f(v0[t]) + e1.x * b2f(v1[t]) + e2.x * b2f(v2[t]) + e3.x * b2f(v3[t]);
    }
    for (; j < ee; j++){
      float2 e0 = lec[j];
      short8 v0 = *(const short8*)&Z1[(long long)__float_as_int(e0.y) * lda + c0];
      #pragma unroll
      for (int t = 0; t < 8; t++) a[t] += e0.x * b2f(v0[t]);
    }
  } else {
    for (int j = s; j < e; j++){
      float2 e0 = ec[j];
      short8 v0 = *(const short8*)&Z1[(long long)__float_as_int(e0.y) * lda + c0];
      #pragma unroll
      for (int t = 0; t < 8; t++) a[t] += e0.x * b2f(v0[t]);
    }
  }
  float xv[8];
  if ((cin & 3) == 0 && c0 + 8 <= cin){
    f32x4 xa = *(const f32x4*)&x[(long long)node * cin + c0];
    f32x4 xb = *(const f32x4*)&x[(long long)node * cin + c0 + 4];
    xv[0] = xa[0]; xv[1] = xa[1]; xv[2] = xa[2]; xv[3] = xa[3];
    xv[4] = xb[0]; xv[5] = xb[1]; xv[6] = xb[2]; xv[7] = xb[3];
  } else {
    #pragma unroll
    for (int t = 0; t < 8; t++){
      int c = c0 + t;
      xv[t] = (c < cin) ? x[(long long)node * cin + c] : 0.0f;
    }
  }
  short8 o;
  #pragma unroll
  for (int t = 0; t < 8; t++) o[t] = f2b(2.0f * a[t] - xv[t]);
  *(short8*)&Z2[(long long)node * lda + c0] = o;
}

// ---------------- layer-0 narrow lhat variants: lda=96, 12 lanes/node ---------
__global__ __launch_bounds__(256)
void k_lhat1v96(const short* X, const int* offs, const float2* ec, short* Z1){
  __shared__ float2 lec[ECAP];
  int gl0 = blockIdx.x * 256;
  int gl = gl0 + threadIdx.x;
  int node = gl / 12;
  int node0 = gl0 / 12;
  int nodeL = (gl0 + 255) / 12;
  if (nodeL > N_NODES - 1) nodeL = N_NODES - 1;
  int s0 = 0;
  int cnt = 0;
  if (node0 < N_NODES){
    s0 = offs[node0];
    cnt = offs[nodeL + 1] - s0;
  }
  int useLds = (cnt <= ECAP);
  if (useLds){
    for (int i = threadIdx.x; i < cnt; i += 256)
      lec[i] = ec[s0 + i];
  }
  __syncthreads();
  if (node >= N_NODES) return;
  int c0 = (gl - node * 12) * 8;
  int s = offs[node];
  int e = offs[node + 1];
  float a[8];
  #pragma unroll
  for (int t = 0; t < 8; t++) a[t] = 0.0f;
  if (useLds){
    int j = s - s0;
    int ee = e - s0;
    for (; j + 4 <= ee; j += 4){
      float2 e0 = lec[j];     float2 e1 = lec[j + 1];
      float2 e2 = lec[j + 2]; float2 e3 = lec[j + 3];
      short8 v0 = *(const short8*)&X[(long long)__float_as_int(e0.y) * 96 + c0];
      short8 v1 = *(const short8*)&X[(long long)__float_as_int(e1.y) * 96 + c0];
      short8 v2 = *(const short8*)&X[(long long)__float_as_int(e2.y) * 96 + c0];
      short8 v3 = *(const short8*)&X[(long long)__float_as_int(e3.y) * 96 + c0];
      #pragma unroll
      for (int t = 0; t < 8; t++)
        a[t] += e0.x * b2f(v0[t]) + e1.x * b2f(v1[t]) + e2.x * b2f(v2[t]) + e3.x * b2f(v3[t]);
    }
    for (; j < ee; j++){
      float2 e0 = lec[j];
      short8 v0 = *(const short8*)&X[(long long)__float_as_int(e0.y) * 96 + c0];
      #pragma unroll
      for (int t = 0; t < 8; t++) a[t] += e0.x * b2f(v0[t]);
    }
  } else {
    for (int j = s; j < e; j++){
      float2 e0 = ec[j];
      short8 v0 = *(const short8*)&X[(long long)__float_as_int(e0.y) * 96 + c0];
      #pragma unroll
      for (int t = 0; t < 8; t++) a[t] += e0.x * b2f(v0[t]);
    }
  }
  short8 o;
  #pragma unroll
  for (int t = 0; t < 8; t++) o[t] = f2b(a[t]);
  *(short8*)&Z1[(long long)node * 96 + c0] = o;
}

__global__ __launch_bounds__(256)
void k_lhat2v96(const float* x, const short* Z1, const int* offs,
                const float2* ec, short* Z2){
  __shared__ float2 lec[ECAP];
  int gl0 = blockIdx.x * 256;
  int gl = gl0 + threadIdx.x;
  int node = gl / 12;
  int node0 = gl0 / 12;
  int nodeL = (gl0 + 255) / 12;
  if (nodeL > N_NODES - 1) nodeL = N_NODES - 1;
  int s0 = 0;
  int cnt = 0;
  if (node0 < N_NODES){
    s0 = offs[node0];
    cnt = offs[nodeL + 1] - s0;
  }
  int useLds = (cnt <= ECAP);
  if (useLds){
    for (int i = threadIdx.x; i < cnt; i += 256)
      lec[i] = ec[s0 + i];
  }
  __syncthreads();
  if (node >= N_NODES) return;
  int c0 = (gl - node * 12) * 8;
  int s = offs[node];
  int e = offs[node + 1];
  float a[8];
  #pragma unroll
  for (int t = 0; t < 8; t++) a[t] = 0.0f;
  if (useLds){
    int j = s - s0;
    int ee = e - s0;
    for (; j + 4 <= ee; j += 4){
      float2 e0 = lec[j];     float2 e1 = lec[j + 1];
      float2 e2 = lec[j + 2]; float2 e3 = lec[j + 3];
      short8 v0 = *(const short8*)&Z1[(long long)__float_as_int(e0.y) * 96 + c0];
      short8 v1 = *(const short8*)&Z1[(long long)__float_as_int(e1.y) * 96 + c0];
      short8 v2 = *(const short8*)&Z1[(long long)__float_as_int(e2.y) * 96 + c0];
      short8 v3 = *(const short8*)&Z1[(long long)__float_as_int(e3.y) * 96 + c0];
      #pragma unroll
      for (int t = 0; t < 8; t++)
        a[t] += e0.x * b2f(v0[t]) + e1.x * b2f(v1[t]) + e2.x * b2f(v2[t]) + e3.x * b2f(v3[t]);
    }
    for (; j < ee; j++){
      float2 e0 = lec[j];
      short8 v0 = *(const short8*)&Z1[(long long)__float_as_int(e0.y) * 96 + c0];
      #pragma unroll
      for (int t = 0; t < 8; t++) a[t] += e0.x * b2f(v0[t]);
    }
  } else {
    for (int j = s; j < e; j++){
      float2 e0 = ec[j];
      short8 v0 = *(const short8*)&Z1[(long long)__float_as_int(e0.y) * 96 + c0];
      #pragma unroll
      for (int t = 0; t < 8; t++) a[t] += e0.x * b2f(v0[t]);
    }
  }
  float xv[8];
  #pragma unroll
  for (int t = 0; t < 8; t++){
    int c = c0 + t;
    xv[t] = (c < 86) ? x[(long long)node * 86 + c] : 0.0f;
  }
  short8 o;
  #pragma unroll
  for (int t = 0; t < 8; t++) o[t] = f2b(2.0f * a[t] - xv[t]);
  *(short8*)&Z2[(long long)node * 96 + c0] = o;
}

// ---------------- MFMA GEMM (r14-proven: single-buffer, unfused) --------------
__global__ __launch_bounds__(256)
void k_gemm(const short* A0, const short* A1, const short* A2,
            const short* BT,   // cout x 3Kext bf16 (row-major, K-contig)
            const float* bias, float* C, int lda, int Kext, int cout){
  __shared__ short aLds[128 * 32];
  __shared__ short bLds[128 * 32];
  int tid = threadIdx.x;
  int lane = tid & 63;
  int wave = tid >> 6;          // 0..3
  int wm = wave >> 1;
  int wn = wave & 1;
  int bm0 = blockIdx.x * 128;
  int bn0 = blockIdx.y * 128;
  int Kpad3 = 3 * Kext;

  int l4 = lane >> 2;                       // row within chunk 0..15
  int slotSrc = (lane & 3) ^ (l4 & 3);      // pre-swizzled source col slot

  f32x4 acc[4][4];
  for (int m = 0; m < 4; m++)
    for (int n = 0; n < 4; n++)
      acc[m][n] = (f32x4){0.0f, 0.0f, 0.0f, 0.0f};

  for (int g = 0; g < 3; g++){
    const short* Ag = (g == 0) ? A0 : ((g == 1) ? A1 : A2);
    const short* Bg = BT + g * Kext;
    for (int kt = 0; kt < Kext; kt += 32){
      #pragma unroll
      for (int cc = 0; cc < 2; cc++){
        int c = wave * 2 + cc;
        int row = c * 16 + l4;
        gload16(&Ag[(long long)(bm0 + row) * lda + kt + slotSrc * 8], &aLds[c * 512]);
        gload16(&Bg[(long long)(bn0 + row) * Kpad3 + kt + slotSrc * 8], &bLds[c * 512]);
      }
      __syncthreads();
      short8 af[4];
      short8 bfr[4];
      #pragma unroll
      for (int m = 0; m < 4; m++){
        int row = wm * 64 + m * 16 + (lane & 15);
        int slot = (lane >> 4) ^ (row & 3);
        af[m] = *(const short8*)&aLds[row * 32 + slot * 8];
      }
      #pragma unroll
      for (int n = 0; n < 4; n++){
        int row = wn * 64 + n * 16 + (lane & 15);
        int slot = (lane >> 4) ^ (row & 3);
        bfr[n] = *(const short8*)&bLds[row * 32 + slot * 8];
      }
      #pragma unroll
      for (int m = 0; m < 4; m++)
        #pragma unroll
        for (int n = 0; n < 4; n++)
          acc[m][n] = __builtin_amdgcn_mfma_f32_16x16x32_bf16(af[m], bfr[n], acc[m][n], 0, 0, 0);
      __syncthreads();
    }
  }

  for (int m = 0; m < 4; m++){
    for (int n = 0; n < 4; n++){
      int gc = bn0 + wn * 64 + n * 16 + (lane & 15);
      float bv = bias[gc];
      for (int r = 0; r < 4; r++){
        int gr = bm0 + wm * 64 + m * 16 + (lane >> 4) * 4 + r;
        if (gr < N_NODES){
          float v2 = acc[m][n][r] + bv;
          if (v2 < 0.0f) v2 = 0.0f;
          C[(long long)gr * cout + gc] = v2;
        }
      }
    }
  }
}

extern "C" void kernel_launch(void* const* d_in, const int* in_sizes, int n_in,
                              void* d_out, int out_size, void* d_ws, size_t ws_size,
                              hipStream_t stream){
  const float* v = (const float*)d_in[0];
  const int* edges = (const int*)d_in[1];
  const int* row = edges;
  const int* col = edges + N_EDGES;

  const float* W00 = (const float*)d_in[2];
  const float* W01 = (const float*)d_in[3];
  const float* W02 = (const float*)d_in[4];
  const float* b0  = (const float*)d_in[5];
  const float* W10 = (const float*)d_in[6];
  const float* W11 = (const float*)d_in[7];
  const float* W12 = (const float*)d_in[8];
  const float* b1  = (const float*)d_in[9];
  const float* W20 = (const float*)d_in[10];
  const float* W21 = (const float*)d_in[11];
  const float* W22 = (const float*)d_in[12];
  const float* b2  = (const float*)d_in[13];

  // workspace layout (byte offsets, 256-aligned; ~36 MB)
  char* ws = (char*)d_ws;
  int* deg    = (int*)(ws + 0);                   // 20000 ints
  int* cursor = (int*)(ws + 80128);               // 20000
  int* offs   = (int*)(ws + 160256);              // 20001
  int* bsum   = (int*)(ws + 240640);              // 128
  float* dinv = (float*)(ws + 241152);            // 20000
  float2* ec  = (float2*)(ws + 321280);           // 320000 float2 = 2.56 MB
  short* B0  = (short*)(ws + 2881536);                         // M_PAD*256 bf16
  short* B1  = (short*)(ws + 2881536 + 10289152);
  short* B2  = (short*)(ws + 2881536 + 2 * 10289152);
  short* WT0 = (short*)(ws + 2881536 + 3 * 10289152);          // 128*288 bf16
  short* WT1 = (short*)(ws + 2881536 + 3 * 10289152 + 73728);  // 256*384 bf16
  short* WT2 = (short*)(ws + 2881536 + 3 * 10289152 + 73728 + 196608); // 512*768

  float* out = (float*)d_out;
  float* x1 = out;
  float* x2 = out + (long long)N_NODES * 128;
  float* x3 = out + (long long)N_NODES * (128 + 256);

  // CSR + weights + L0 staging (merged)
  k_zero_i<<<(40064 + 255) / 256, 256, 0, stream>>>(deg, 40064);  // deg+cursor
  k_mega<<<4256, 256, 0, stream>>>(row, deg,
                                   W00, W01, W02, WT0,
                                   W10, W11, W12, WT1,
                                   W20, W21, W22, WT2,
                                   v, B0);
  k_scan1<<<NB_SCAN, 256, 0, stream>>>(deg, offs, bsum);
  k_scan2<<<1, 128, 0, stream>>>(bsum);
  k_scan3<<<NB_SCAN, 256, 0, stream>>>(deg, offs, bsum, dinv);
  k_fill<<<(N_EDGES + 255) / 256, 256, 0, stream>>>(row, col, offs, cursor, dinv, ec);

  // grids
  int gNd96  = (int)(((long long)N_NODES * 12 + 255) / 256);
  int gXb128 = (int)(((long long)M_PAD * 16 + 255) / 256);
  int gXb256 = (int)(((long long)M_PAD * 32 + 255) / 256);
  int gNd128 = (int)(((long long)N_NODES * 16 + 255) / 256);
  int gNd256 = (int)(((long long)N_NODES * 32 + 255) / 256);

  // ---- layer 0: cin=86, Kext=96, lda=96, cout=128 (B0 staged by k_mega) ----
  k_lhat1v96<<<gNd96, 256, 0, stream>>>(B0, offs, ec, B1);
  k_lhat2v96<<<gNd96, 256, 0, stream>>>(v, B1, offs, ec, B2);
  {
    dim3 g(M_PAD / 128, 1);
    k_gemm<<<g, 256, 0, stream>>>(B0, B1, B2, WT0, b0, x1, 96, 96, 128);
  }

  // ---- layer 1: cin=128, Kext=128, lda=128, cout=256 ----
  k_xbv<<<gXb128, 256, 0, stream>>>(x1, B0, 128, 4, 128);
  k_lhat1v<<<gNd128, 256, 0, stream>>>(B0, offs, ec, B1, 4, 128);
  k_lhat2v<<<gNd128, 256, 0, stream>>>(x1, B1, offs, ec, B2, 128, 4, 128);
  {
    dim3 g(M_PAD / 128, 2);
    k_gemm<<<g, 256, 0, stream>>>(B0, B1, B2, WT1, b1, x2, 128, 128, 256);
  }

  // ---- layer 2: cin=256, Kext=256, lda=256, cout=512 ----
  k_xbv<<<gXb256, 256, 0, stream>>>(x2, B0, 256, 5, 256);
  k_lhat1v<<<gNd256, 256, 0, stream>>>(B0, offs, ec, B1, 5, 256);
  k_lhat2v<<<gNd256, 256, 0, stream>>>(x2, B1, offs, ec, B2, 256, 5, 256);
  {
    dim3 g(M_PAD / 128, 4);
    k_gemm<<<g, 256, 0, stream>>>(B0, B1, B2, WT2, b2, x3, 256, 256, 512);
  }
}